// Round 6
// baseline (1607.095 us; speedup 1.0000x reference)
//
#include <hip/hip_runtime.h>
#include <math.h>

#define FEAT 128
#define HID  64
#define BSH  7                 // 128 dst-nodes per bucket
#define BNODES (1 << BSH)
#define PB   256               // partition blocks
#define SRCM ((1 << 25) - 1)   // src in low 25 bits, dst_local in high 7

// ---------------- edge partition by dst-bucket ----------------
// table layout: table[k*PB + b] = count of block b's edges in bucket k
// (bucket-major so the scanned offsets group edges by bucket).

__global__ void part_hist_k(const int* __restrict__ dst, int* __restrict__ table,
                            int e, int nb) {
    __shared__ int lcnt[1024];
    for (int i = threadIdx.x; i < nb; i += 256) lcnt[i] = 0;
    __syncthreads();
    int eb = (e + PB - 1) / PB;
    int lo = blockIdx.x * eb, hi = min(lo + eb, e);
    for (int i = lo + threadIdx.x; i < hi; i += 256)
        atomicAdd(&lcnt[dst[i] >> BSH], 1);
    __syncthreads();
    for (int k = threadIdx.x; k < nb; k += 256)
        table[k * PB + blockIdx.x] = lcnt[k];
}

__global__ void scan1_k(int* __restrict__ data, int* __restrict__ aux, int L) {
    __shared__ int s[1024];
    int gid = blockIdx.x * 1024 + threadIdx.x;
    int v = (gid < L) ? data[gid] : 0;
    s[threadIdx.x] = v;
    __syncthreads();
    for (int off = 1; off < 1024; off <<= 1) {
        int t = (threadIdx.x >= off) ? s[threadIdx.x - off] : 0;
        __syncthreads();
        s[threadIdx.x] += t;
        __syncthreads();
    }
    if (gid < L) data[gid] = s[threadIdx.x] - v;            // exclusive in block
    if (threadIdx.x == 1023) aux[blockIdx.x] = s[1023];     // block total
}

__global__ void scan2_k(int* aux, int naux) {
    __shared__ int s[1024];
    int v = (threadIdx.x < naux) ? aux[threadIdx.x] : 0;
    s[threadIdx.x] = v;
    __syncthreads();
    for (int off = 1; off < 1024; off <<= 1) {
        int t = (threadIdx.x >= off) ? s[threadIdx.x - off] : 0;
        __syncthreads();
        s[threadIdx.x] += t;
        __syncthreads();
    }
    if (threadIdx.x < naux) aux[threadIdx.x] = s[threadIdx.x] - v;
}

__global__ void scan3_k(int* __restrict__ data, const int* __restrict__ aux, int L) {
    int i = blockIdx.x * 1024 + threadIdx.x;
    if (i < L) data[i] += aux[blockIdx.x];
}

__global__ void part_scatter_k(const int* __restrict__ src, const int* __restrict__ dst,
                               const int* __restrict__ table, unsigned* __restrict__ packed,
                               int e, int nb) {
    __shared__ int loff[1024];
    for (int k = threadIdx.x; k < nb; k += 256) loff[k] = table[k * PB + blockIdx.x];
    __syncthreads();
    int eb = (e + PB - 1) / PB;
    int lo = blockIdx.x * eb, hi = min(lo + eb, e);
    for (int i = lo + threadIdx.x; i < hi; i += 256) {
        int d = dst[i];
        int p = atomicAdd(&loff[d >> BSH], 1);
        packed[p] = ((unsigned)(d & (BNODES - 1)) << 25) | (unsigned)src[i];
    }
}

// per-bucket degree count -> dinv (deg = 1 self-loop + in-degree)
__global__ void deginv_k(const unsigned* __restrict__ packed, const int* __restrict__ table,
                         float* __restrict__ dinv, int n, int e, int nb) {
    __shared__ int dcnt[BNODES];
    int k = blockIdx.x;
    if (threadIdx.x < BNODES) dcnt[threadIdx.x] = 0;
    __syncthreads();
    int bs = table[k * PB];
    int be = (k + 1 < nb) ? table[(k + 1) * PB] : e;
    for (int i = bs + threadIdx.x; i < be; i += 256)
        atomicAdd(&dcnt[packed[i] >> 25], 1);
    __syncthreads();
    if (threadIdx.x < BNODES) {
        int node = k * BNODES + threadIdx.x;
        if (node < n) dinv[node] = 1.0f / sqrtf(1.0f + (float)dcnt[threadIdx.x]);
    }
}

// ---------------- dense transform: out[n,64] = (X[n,K] @ W[K,64]) * dinv[row] ----------------

template<int K>
__global__ __launch_bounds__(256, 2) void gemm_tile_k(const float* __restrict__ X,
                                                      const float* __restrict__ W,
                                                      const float* __restrict__ dinv,
                                                      float* __restrict__ out, int n) {
    __shared__ float sX[64][K + 4];
    __shared__ float sW[K][64];
    const int row0 = blockIdx.x * 64;
    const int t  = threadIdx.x;
    const int tx = t & 15;
    const int ty = t >> 4;
    constexpr int KSH = (K == 128) ? 7 : 6;

    const float* xb = X + (size_t)row0 * K;
#pragma unroll
    for (int it = 0; it < K / 16; ++it) {
        int fl = it * 1024 + t * 4;
        int r  = fl >> KSH;
        int k  = fl & (K - 1);
        float4 v = make_float4(0.f, 0.f, 0.f, 0.f);
        if (row0 + r < n) v = *(const float4*)(xb + fl);
        *(float4*)&sX[r][k] = v;
    }
#pragma unroll
    for (int it = 0; it < K / 16; ++it) {
        int fl = it * 1024 + t * 4;
        *(float4*)&sW[fl >> 6][fl & 63] = *(const float4*)(W + fl);
    }
    __syncthreads();

    float acc[4][4] = {};
#pragma unroll 8
    for (int k = 0; k < K; k += 4) {
        float4 a[4], b[4];
#pragma unroll
        for (int i = 0; i < 4; i++) a[i] = *(float4*)&sX[ty * 4 + i][k];
#pragma unroll
        for (int j = 0; j < 4; j++) b[j] = *(float4*)&sW[k + j][tx * 4];
#pragma unroll
        for (int i = 0; i < 4; i++) {
            acc[i][0] = fmaf(a[i].x, b[0].x, acc[i][0]);
            acc[i][1] = fmaf(a[i].x, b[0].y, acc[i][1]);
            acc[i][2] = fmaf(a[i].x, b[0].z, acc[i][2]);
            acc[i][3] = fmaf(a[i].x, b[0].w, acc[i][3]);
            acc[i][0] = fmaf(a[i].y, b[1].x, acc[i][0]);
            acc[i][1] = fmaf(a[i].y, b[1].y, acc[i][1]);
            acc[i][2] = fmaf(a[i].y, b[1].z, acc[i][2]);
            acc[i][3] = fmaf(a[i].y, b[1].w, acc[i][3]);
            acc[i][0] = fmaf(a[i].z, b[2].x, acc[i][0]);
            acc[i][1] = fmaf(a[i].z, b[2].y, acc[i][1]);
            acc[i][2] = fmaf(a[i].z, b[2].z, acc[i][2]);
            acc[i][3] = fmaf(a[i].z, b[2].w, acc[i][3]);
            acc[i][0] = fmaf(a[i].w, b[3].x, acc[i][0]);
            acc[i][1] = fmaf(a[i].w, b[3].y, acc[i][1]);
            acc[i][2] = fmaf(a[i].w, b[3].z, acc[i][2]);
            acc[i][3] = fmaf(a[i].w, b[3].w, acc[i][3]);
        }
    }

#pragma unroll
    for (int i = 0; i < 4; i++) {
        int gr = row0 + ty * 4 + i;
        if (gr < n) {
            float sc = dinv[gr];
            *(float4*)(out + (size_t)gr * HID + tx * 4) =
                make_float4(acc[i][0] * sc, acc[i][1] * sc, acc[i][2] * sc, acc[i][3] * sc);
        }
    }
}

// ---------------- bucket aggregation (fused selfloop + bias + relu) ----------------
// Block k owns dst nodes [k*128, k*128+128): LDS accumulator 128x64 floats.
// Waves walk the bucket's contiguous packed edges; lane = feature.
// h[d] = relu( dinv[d] * (acc[d] + tS[d]) + b )

__global__ __launch_bounds__(256, 2) void bucket_agg_k(const float* __restrict__ tS,
                         const unsigned* __restrict__ packed, const int* __restrict__ table,
                         const float* __restrict__ dinv, const float* __restrict__ b,
                         float* __restrict__ out, int n, int e, int nb) {
    __shared__ float acc[BNODES * HID];
    const int k = blockIdx.x;
    const int t = threadIdx.x;
    const int lane = t & 63;
    const int wave = t >> 6;

    for (int i = t * 4; i < BNODES * HID; i += 1024)
        *(float4*)&acc[i] = make_float4(0.f, 0.f, 0.f, 0.f);
    __syncthreads();

    const int bs = table[k * PB];
    const int be = (k + 1 < nb) ? table[(k + 1) * PB] : e;
    const float* tl = tS + lane;

    int i = bs + wave;
    for (; i + 12 < be; i += 16) {
        unsigned u0 = packed[i], u1 = packed[i + 4], u2 = packed[i + 8], u3 = packed[i + 12];
        float v0 = tl[(size_t)(u0 & SRCM) * HID];
        float v1 = tl[(size_t)(u1 & SRCM) * HID];
        float v2 = tl[(size_t)(u2 & SRCM) * HID];
        float v3 = tl[(size_t)(u3 & SRCM) * HID];
        atomicAdd(&acc[(u0 >> 25) * HID + lane], v0);
        atomicAdd(&acc[(u1 >> 25) * HID + lane], v1);
        atomicAdd(&acc[(u2 >> 25) * HID + lane], v2);
        atomicAdd(&acc[(u3 >> 25) * HID + lane], v3);
    }
    for (; i < be; i += 4) {
        unsigned u = packed[i];
        float v = tl[(size_t)(u & SRCM) * HID];
        atomicAdd(&acc[(u >> 25) * HID + lane], v);
    }
    __syncthreads();

    const int base = k * BNODES;
    for (int idx = t; idx < BNODES * HID; idx += 256) {
        int node = base + (idx >> 6);
        if (node < n) {
            int l = idx & 63;
            float s = acc[idx] + tS[(size_t)node * HID + l];
            out[(size_t)node * HID + l] = fmaxf(fmaf(dinv[node], s, b[l]), 0.0f);
        }
    }
}

// ---------------- heads ----------------

__global__ void pool_k(const float* __restrict__ h, const int* __restrict__ batch,
                       float* __restrict__ pooled, float* __restrict__ counts, int n) {
    int lane = threadIdx.x & 63;
    int wave = threadIdx.x >> 6;
    int start = blockIdx.x * 64 + wave * 16;
    int end   = min(start + 16, n);
    if (start >= end) return;
    float acc = 0.0f;
    int curg = -1, cnt = 0;
    for (int i = start; i < end; i++) {
        int g = batch[i];
        if (g != curg) {
            if (curg >= 0) {
                atomicAdd(&pooled[curg * HID + lane], acc);
                if (lane == 0) atomicAdd(&counts[curg], (float)cnt);
            }
            curg = g; acc = 0.0f; cnt = 0;
        }
        acc += h[(size_t)i * HID + lane];
        cnt++;
    }
    atomicAdd(&pooled[curg * HID + lane], acc);
    if (lane == 0) atomicAdd(&counts[curg], (float)cnt);
}

__global__ void logits_k(const float* __restrict__ h, const float* __restrict__ Wa,
                         const float* __restrict__ ba, float* __restrict__ out, int n) {
    __shared__ float sWa[HID];
    if (threadIdx.x < HID) sWa[threadIdx.x] = Wa[threadIdx.x];
    __syncthreads();
    int i = blockIdx.x * blockDim.x + threadIdx.x;
    if (i >= n) return;
    const float4* hp = (const float4*)(h + (size_t)i * HID);
    float acc = 0.0f;
#pragma unroll
    for (int k = 0; k < HID / 4; k++) {
        float4 v = hp[k];
        acc = fmaf(v.x, sWa[4 * k + 0],
              fmaf(v.y, sWa[4 * k + 1],
              fmaf(v.z, sWa[4 * k + 2],
              fmaf(v.w, sWa[4 * k + 3], acc))));
    }
    out[i] = acc + ba[0];
}

__global__ void value_k(const float* __restrict__ pooled, const float* __restrict__ counts,
                        const float* __restrict__ Wc, const float* __restrict__ bc,
                        float* __restrict__ val, int g) {
    int gw   = (int)((blockIdx.x * (size_t)blockDim.x + threadIdx.x) >> 6);
    int lane = threadIdx.x & 63;
    if (gw >= g) return;
    float cnt = fmaxf(counts[gw], 1.0f);
    float p = (pooled[gw * HID + lane] / cnt) * Wc[lane];
#pragma unroll
    for (int off = 32; off > 0; off >>= 1) p += __shfl_down(p, off);
    if (lane == 0) val[gw] = p + bc[0];
}

extern "C" void kernel_launch(void* const* d_in, const int* in_sizes, int n_in,
                              void* d_out, int out_size, void* d_ws, size_t ws_size,
                              hipStream_t stream) {
    const float* x     = (const float*)d_in[0];
    const int*   ei    = (const int*)d_in[1];
    const int*   batch = (const int*)d_in[2];
    const float* W1    = (const float*)d_in[3];
    const float* b1    = (const float*)d_in[4];
    const float* W2    = (const float*)d_in[5];
    const float* b2    = (const float*)d_in[6];
    const float* Wa    = (const float*)d_in[7];
    const float* ba    = (const float*)d_in[8];
    const float* Wc    = (const float*)d_in[9];
    const float* bc    = (const float*)d_in[10];

    const int n = in_sizes[0] / FEAT;   // 100000
    const int e = in_sizes[1] / 2;      // 1600000
    const int g = out_size - n;         // 64
    const int* src = ei;
    const int* dst = ei + e;

    const int nb = (n + BNODES - 1) >> BSH;   // buckets (782)
    const int L  = nb * PB;                    // offset table length

    // workspace layout
    float*    ws     = (float*)d_ws;
    float*    dinv   = ws;                               // n
    float*    bufA   = dinv + n;                         // n*HID  (tS)
    float*    bufB   = bufA + (size_t)n * HID;           // n*HID  (h)
    float*    pooled = bufB + (size_t)n * HID;           // g*HID
    float*    counts = pooled + (size_t)g * HID;         // g
    int*      table  = (int*)(counts + g);               // L
    int*      aux    = table + L;                        // 1024
    unsigned* packed = (unsigned*)(aux + 1024);          // e

    const int B = 256;
    const int nbN   = (n + B - 1) / B;
    const int gridT = (n + 63) / 64;
    const int nb1   = (L + 1023) / 1024;   // scan blocks (<=1024)

    hipMemsetAsync(pooled, 0, (size_t)(g * HID + g) * sizeof(float), stream);

    // edge partition by dst bucket + degree/dinv
    part_hist_k<<<PB, B, 0, stream>>>(dst, table, e, nb);
    scan1_k<<<nb1, 1024, 0, stream>>>(table, aux, L);
    scan2_k<<<1, 1024, 0, stream>>>(aux, nb1);
    scan3_k<<<nb1, 1024, 0, stream>>>(table, aux, L);
    part_scatter_k<<<PB, B, 0, stream>>>(src, dst, table, packed, e, nb);
    deginv_k<<<nb, B, 0, stream>>>(packed, table, dinv, n, e, nb);

    // layer 1
    gemm_tile_k<FEAT><<<gridT, B, 0, stream>>>(x, W1, dinv, bufA, n);
    bucket_agg_k<<<nb, B, 0, stream>>>(bufA, packed, table, dinv, b1, bufB, n, e, nb);

    // layer 2
    gemm_tile_k<HID><<<gridT, B, 0, stream>>>(bufB, W2, dinv, bufA, n);
    bucket_agg_k<<<nb, B, 0, stream>>>(bufA, packed, table, dinv, b2, bufB, n, e, nb);

    // heads
    pool_k<<<(n + 63) / 64, B, 0, stream>>>(bufB, batch, pooled, counts, n);
    logits_k<<<nbN, B, 0, stream>>>(bufB, Wa, ba, (float*)d_out, n);
    value_k<<<(g * 64 + B - 1) / B, B, 0, stream>>>(pooled, counts, Wc, bc, (float*)d_out + n, g);
}

// Round 7
// 383.755 us; speedup vs baseline: 4.1878x; 4.1878x over previous
//
#include <hip/hip_runtime.h>
#include <math.h>

#define FEAT 128
#define HID  64
#define BSH  7                 // 128 dst-nodes per bucket
#define BNODES (1 << BSH)
#define PB   256               // partition blocks
#define SRCM ((1u << 25) - 1)  // src in low 25 bits, dst_local in high 7

// ---------------- stage 1: edge partition by dst-bucket ----------------
// table[k*PB + b] = count of partition-block b's edges in bucket k
// (bucket-major, so scanned offsets give each (bucket, block) a contiguous,
// block-EXCLUSIVE output range -> no write-line sharing).

__global__ void part_hist_k(const int* __restrict__ dst, int* __restrict__ table,
                            int e, int nb) {
    __shared__ int lcnt[1024];
    for (int i = threadIdx.x; i < nb; i += 256) lcnt[i] = 0;
    __syncthreads();
    int eb = (e + PB - 1) / PB;
    int lo = blockIdx.x * eb, hi = min(lo + eb, e);
    for (int i = lo + threadIdx.x; i < hi; i += 256)
        atomicAdd(&lcnt[dst[i] >> BSH], 1);
    __syncthreads();
    for (int k = threadIdx.x; k < nb; k += 256)
        table[k * PB + blockIdx.x] = lcnt[k];
}

__global__ void scan1_k(int* __restrict__ data, int* __restrict__ aux, int L) {
    __shared__ int s[1024];
    int gid = blockIdx.x * 1024 + threadIdx.x;
    int v = (gid < L) ? data[gid] : 0;
    s[threadIdx.x] = v;
    __syncthreads();
    for (int off = 1; off < 1024; off <<= 1) {
        int t = (threadIdx.x >= off) ? s[threadIdx.x - off] : 0;
        __syncthreads();
        s[threadIdx.x] += t;
        __syncthreads();
    }
    if (gid < L) data[gid] = s[threadIdx.x] - v;            // exclusive in block
    if (threadIdx.x == 1023) aux[blockIdx.x] = s[1023];     // block total
}

__global__ void scan2_k(int* aux, int naux) {
    __shared__ int s[1024];
    int v = (threadIdx.x < naux) ? aux[threadIdx.x] : 0;
    s[threadIdx.x] = v;
    __syncthreads();
    for (int off = 1; off < 1024; off <<= 1) {
        int t = (threadIdx.x >= off) ? s[threadIdx.x - off] : 0;
        __syncthreads();
        s[threadIdx.x] += t;
        __syncthreads();
    }
    if (threadIdx.x < naux) aux[threadIdx.x] = s[threadIdx.x] - v;
}

__global__ void scan3_k(int* __restrict__ data, const int* __restrict__ aux, int L) {
    int i = blockIdx.x * 1024 + threadIdx.x;
    if (i < L) data[i] += aux[blockIdx.x];
}

__global__ void part_scatter_k(const int* __restrict__ src, const int* __restrict__ dst,
                               const int* __restrict__ table, unsigned* __restrict__ packed,
                               int e, int nb) {
    __shared__ int loff[1024];
    for (int k = threadIdx.x; k < nb; k += 256) loff[k] = table[k * PB + blockIdx.x];
    __syncthreads();
    int eb = (e + PB - 1) / PB;
    int lo = blockIdx.x * eb, hi = min(lo + eb, e);
    for (int i = lo + threadIdx.x; i < hi; i += 256) {
        int d = dst[i];
        int p = atomicAdd(&loff[d >> BSH], 1);
        packed[p] = ((unsigned)(d & (BNODES - 1)) << 25) | (unsigned)src[i];
    }
}

// ---------------- stage 2: per-bucket counting sort -> per-node CSR + dinv ----
// One block per bucket: LDS histogram of 128 local-dst counters (=in-degree
// -> dinv), LDS exclusive scan, scatter src into the bucket's contiguous col
// region (~8KB, L2-resident -> no write amplification).

__global__ void bucket_sort_k(const unsigned* __restrict__ packed,
                              const int* __restrict__ table,
                              int* __restrict__ col, int* __restrict__ rowptr,
                              float* __restrict__ dinv, int n, int e, int nb) {
    __shared__ int cnt[BNODES];
    __shared__ int s[BNODES];
    __shared__ int cur[BNODES];
    const int k = blockIdx.x;
    const int t = threadIdx.x;
    if (t < BNODES) cnt[t] = 0;
    __syncthreads();
    const int bs = table[k * PB];
    const int be = (k + 1 < nb) ? table[(k + 1) * PB] : e;
    for (int i = bs + t; i < be; i += 256)
        atomicAdd(&cnt[packed[i] >> 25], 1);
    __syncthreads();
    // exclusive scan over BNODES counters
    if (t < BNODES) s[t] = cnt[t];
    __syncthreads();
    for (int off = 1; off < BNODES; off <<= 1) {
        int v = (t < BNODES && t >= off) ? s[t - off] : 0;
        __syncthreads();
        if (t < BNODES) s[t] += v;
        __syncthreads();
    }
    if (t < BNODES) {
        int base = bs + s[t] - cnt[t];
        cur[t] = base;
        int node = (k << BSH) + t;
        if (node < n) {
            rowptr[node] = base;
            dinv[node] = 1.0f / sqrtf(1.0f + (float)cnt[t]);
            if (node == n - 1) rowptr[n] = base + cnt[t];
        }
    }
    __syncthreads();
    for (int i = bs + t; i < be; i += 256) {
        unsigned u = packed[i];
        int p = atomicAdd(&cur[u >> 25], 1);
        col[p] = (int)(u & SRCM);
    }
}

// ---------------- dense transform: out[n,64] = (X[n,K] @ W[K,64]) * dinv[row] ----------------

template<int K>
__global__ __launch_bounds__(256, 2) void gemm_tile_k(const float* __restrict__ X,
                                                      const float* __restrict__ W,
                                                      const float* __restrict__ dinv,
                                                      float* __restrict__ out, int n) {
    __shared__ float sX[64][K + 4];
    __shared__ float sW[K][64];
    const int row0 = blockIdx.x * 64;
    const int t  = threadIdx.x;
    const int tx = t & 15;
    const int ty = t >> 4;
    constexpr int KSH = (K == 128) ? 7 : 6;

    const float* xb = X + (size_t)row0 * K;
#pragma unroll
    for (int it = 0; it < K / 16; ++it) {
        int fl = it * 1024 + t * 4;
        int r  = fl >> KSH;
        int k  = fl & (K - 1);
        float4 v = make_float4(0.f, 0.f, 0.f, 0.f);
        if (row0 + r < n) v = *(const float4*)(xb + fl);
        *(float4*)&sX[r][k] = v;
    }
#pragma unroll
    for (int it = 0; it < K / 16; ++it) {
        int fl = it * 1024 + t * 4;
        *(float4*)&sW[fl >> 6][fl & 63] = *(const float4*)(W + fl);
    }
    __syncthreads();

    float acc[4][4] = {};
#pragma unroll 8
    for (int k = 0; k < K; k += 4) {
        float4 a[4], b[4];
#pragma unroll
        for (int i = 0; i < 4; i++) a[i] = *(float4*)&sX[ty * 4 + i][k];
#pragma unroll
        for (int j = 0; j < 4; j++) b[j] = *(float4*)&sW[k + j][tx * 4];
#pragma unroll
        for (int i = 0; i < 4; i++) {
            acc[i][0] = fmaf(a[i].x, b[0].x, acc[i][0]);
            acc[i][1] = fmaf(a[i].x, b[0].y, acc[i][1]);
            acc[i][2] = fmaf(a[i].x, b[0].z, acc[i][2]);
            acc[i][3] = fmaf(a[i].x, b[0].w, acc[i][3]);
            acc[i][0] = fmaf(a[i].y, b[1].x, acc[i][0]);
            acc[i][1] = fmaf(a[i].y, b[1].y, acc[i][1]);
            acc[i][2] = fmaf(a[i].y, b[1].z, acc[i][2]);
            acc[i][3] = fmaf(a[i].y, b[1].w, acc[i][3]);
            acc[i][0] = fmaf(a[i].z, b[2].x, acc[i][0]);
            acc[i][1] = fmaf(a[i].z, b[2].y, acc[i][1]);
            acc[i][2] = fmaf(a[i].z, b[2].z, acc[i][2]);
            acc[i][3] = fmaf(a[i].z, b[2].w, acc[i][3]);
            acc[i][0] = fmaf(a[i].w, b[3].x, acc[i][0]);
            acc[i][1] = fmaf(a[i].w, b[3].y, acc[i][1]);
            acc[i][2] = fmaf(a[i].w, b[3].z, acc[i][2]);
            acc[i][3] = fmaf(a[i].w, b[3].w, acc[i][3]);
        }
    }

#pragma unroll
    for (int i = 0; i < 4; i++) {
        int gr = row0 + ty * 4 + i;
        if (gr < n) {
            float sc = dinv[gr];
            *(float4*)(out + (size_t)gr * HID + tx * 4) =
                make_float4(acc[i][0] * sc, acc[i][1] * sc, acc[i][2] * sc, acc[i][3] * sc);
        }
    }
}

// ---------------- CSR gather aggregation (fused selfloop + bias + relu) ----------------
// One wave per node (100k waves -> latency fully hidden by TLP).

__global__ void gather_k(const float* __restrict__ tS, const int* __restrict__ rowptr,
                         const int* __restrict__ col, const float* __restrict__ dinv,
                         const float* __restrict__ b, float* __restrict__ out, int n) {
    int node = (int)((blockIdx.x * (size_t)blockDim.x + threadIdx.x) >> 6);
    int lane = threadIdx.x & 63;
    if (node >= n) return;
    int beg = rowptr[node], end = rowptr[node + 1];
    const float* tl = tS + lane;
    float acc = tl[(size_t)node * HID];   // self-loop term
    int e = beg;
    for (; e + 4 <= end; e += 4) {
        int s0 = col[e], s1 = col[e + 1], s2 = col[e + 2], s3 = col[e + 3];
        float v0 = tl[(size_t)s0 * HID];
        float v1 = tl[(size_t)s1 * HID];
        float v2 = tl[(size_t)s2 * HID];
        float v3 = tl[(size_t)s3 * HID];
        acc += (v0 + v1) + (v2 + v3);
    }
    for (; e < end; ++e) acc += tl[(size_t)col[e] * HID];
    out[(size_t)node * HID + lane] = fmaxf(fmaf(dinv[node], acc, b[lane]), 0.0f);
}

// ---------------- heads ----------------

__global__ void pool_k(const float* __restrict__ h, const int* __restrict__ batch,
                       float* __restrict__ pooled, float* __restrict__ counts, int n) {
    int lane = threadIdx.x & 63;
    int wave = threadIdx.x >> 6;
    int start = blockIdx.x * 64 + wave * 16;
    int end   = min(start + 16, n);
    if (start >= end) return;
    float acc = 0.0f;
    int curg = -1, cnt = 0;
    for (int i = start; i < end; i++) {
        int g = batch[i];
        if (g != curg) {
            if (curg >= 0) {
                atomicAdd(&pooled[curg * HID + lane], acc);
                if (lane == 0) atomicAdd(&counts[curg], (float)cnt);
            }
            curg = g; acc = 0.0f; cnt = 0;
        }
        acc += h[(size_t)i * HID + lane];
        cnt++;
    }
    atomicAdd(&pooled[curg * HID + lane], acc);
    if (lane == 0) atomicAdd(&counts[curg], (float)cnt);
}

__global__ void logits_k(const float* __restrict__ h, const float* __restrict__ Wa,
                         const float* __restrict__ ba, float* __restrict__ out, int n) {
    __shared__ float sWa[HID];
    if (threadIdx.x < HID) sWa[threadIdx.x] = Wa[threadIdx.x];
    __syncthreads();
    int i = blockIdx.x * blockDim.x + threadIdx.x;
    if (i >= n) return;
    const float4* hp = (const float4*)(h + (size_t)i * HID);
    float acc = 0.0f;
#pragma unroll
    for (int k = 0; k < HID / 4; k++) {
        float4 v = hp[k];
        acc = fmaf(v.x, sWa[4 * k + 0],
              fmaf(v.y, sWa[4 * k + 1],
              fmaf(v.z, sWa[4 * k + 2],
              fmaf(v.w, sWa[4 * k + 3], acc))));
    }
    out[i] = acc + ba[0];
}

__global__ void value_k(const float* __restrict__ pooled, const float* __restrict__ counts,
                        const float* __restrict__ Wc, const float* __restrict__ bc,
                        float* __restrict__ val, int g) {
    int gw   = (int)((blockIdx.x * (size_t)blockDim.x + threadIdx.x) >> 6);
    int lane = threadIdx.x & 63;
    if (gw >= g) return;
    float cnt = fmaxf(counts[gw], 1.0f);
    float p = (pooled[gw * HID + lane] / cnt) * Wc[lane];
#pragma unroll
    for (int off = 32; off > 0; off >>= 1) p += __shfl_down(p, off);
    if (lane == 0) val[gw] = p + bc[0];
}

extern "C" void kernel_launch(void* const* d_in, const int* in_sizes, int n_in,
                              void* d_out, int out_size, void* d_ws, size_t ws_size,
                              hipStream_t stream) {
    const float* x     = (const float*)d_in[0];
    const int*   ei    = (const int*)d_in[1];
    const int*   batch = (const int*)d_in[2];
    const float* W1    = (const float*)d_in[3];
    const float* b1    = (const float*)d_in[4];
    const float* W2    = (const float*)d_in[5];
    const float* b2    = (const float*)d_in[6];
    const float* Wa    = (const float*)d_in[7];
    const float* ba    = (const float*)d_in[8];
    const float* Wc    = (const float*)d_in[9];
    const float* bc    = (const float*)d_in[10];

    const int n = in_sizes[0] / FEAT;   // 100000
    const int e = in_sizes[1] / 2;      // 1600000
    const int g = out_size - n;         // 64
    const int* src = ei;
    const int* dst = ei + e;

    const int nb = (n + BNODES - 1) >> BSH;   // buckets (782)
    const int L  = nb * PB;                    // offset table length

    // workspace layout (packed aliases bufA: dead before first gemm)
    float*    ws     = (float*)d_ws;
    float*    dinv   = ws;                               // n
    float*    bufA   = dinv + n;                         // n*HID  (tS)
    float*    bufB   = bufA + (size_t)n * HID;           // n*HID  (h)
    float*    pooled = bufB + (size_t)n * HID;           // g*HID
    float*    counts = pooled + (size_t)g * HID;         // g
    int*      table  = (int*)(counts + g);               // L
    int*      aux    = table + L;                        // 1024
    int*      rowptr = aux + 1024;                       // n+1
    int*      col    = rowptr + n + 1;                   // e
    unsigned* packed = (unsigned*)bufA;                  // e (aliased, transient)

    const int B = 256;
    const int nbN   = (n + B - 1) / B;
    const int gridT = (n + 63) / 64;
    const int gridG = (int)(((size_t)n * 64 + B - 1) / B);   // wave per node
    const int nb1   = (L + 1023) / 1024;

    hipMemsetAsync(pooled, 0, (size_t)(g * HID + g) * sizeof(float), stream);

    // two-level CSR build: bucket partition -> in-bucket counting sort
    part_hist_k<<<PB, B, 0, stream>>>(dst, table, e, nb);
    scan1_k<<<nb1, 1024, 0, stream>>>(table, aux, L);
    scan2_k<<<1, 1024, 0, stream>>>(aux, nb1);
    scan3_k<<<nb1, 1024, 0, stream>>>(table, aux, L);
    part_scatter_k<<<PB, B, 0, stream>>>(src, dst, table, packed, e, nb);
    bucket_sort_k<<<nb, B, 0, stream>>>(packed, table, col, rowptr, dinv, n, e, nb);

    // layer 1
    gemm_tile_k<FEAT><<<gridT, B, 0, stream>>>(x, W1, dinv, bufA, n);
    gather_k<<<gridG, B, 0, stream>>>(bufA, rowptr, col, dinv, b1, bufB, n);

    // layer 2
    gemm_tile_k<HID><<<gridT, B, 0, stream>>>(bufB, W2, dinv, bufA, n);
    gather_k<<<gridG, B, 0, stream>>>(bufA, rowptr, col, dinv, b2, bufB, n);

    // heads
    pool_k<<<(n + 63) / 64, B, 0, stream>>>(bufB, batch, pooled, counts, n);
    logits_k<<<nbN, B, 0, stream>>>(bufB, Wa, ba, (float*)d_out, n);
    value_k<<<(g * 64 + B - 1) / B, B, 0, stream>>>(pooled, counts, Wc, bc, (float*)d_out + n, g);
}

// Round 8
// 362.690 us; speedup vs baseline: 4.4310x; 1.0581x over previous
//
#include <hip/hip_runtime.h>
#include <math.h>

#define FEAT 128
#define HID  64
#define BSH  7                 // 128 dst-nodes per bucket
#define BNODES (1 << BSH)
#define PB   256               // partition blocks
#define SRCM ((1u << 25) - 1)  // src in low 25 bits, dst_local in high 7

// ---------------- stage 1: edge partition by dst-bucket ----------------

__global__ void part_hist_k(const int* __restrict__ dst, int* __restrict__ table,
                            int e, int nb) {
    __shared__ int lcnt[1024];
    for (int i = threadIdx.x; i < nb; i += 256) lcnt[i] = 0;
    __syncthreads();
    int eb = (e + PB - 1) / PB;
    int lo = blockIdx.x * eb, hi = min(lo + eb, e);
    for (int i = lo + threadIdx.x; i < hi; i += 256)
        atomicAdd(&lcnt[dst[i] >> BSH], 1);
    __syncthreads();
    for (int k = threadIdx.x; k < nb; k += 256)
        table[k * PB + blockIdx.x] = lcnt[k];
}

__global__ void scan1_k(int* __restrict__ data, int* __restrict__ aux, int L) {
    __shared__ int s[1024];
    int gid = blockIdx.x * 1024 + threadIdx.x;
    int v = (gid < L) ? data[gid] : 0;
    s[threadIdx.x] = v;
    __syncthreads();
    for (int off = 1; off < 1024; off <<= 1) {
        int t = (threadIdx.x >= off) ? s[threadIdx.x - off] : 0;
        __syncthreads();
        s[threadIdx.x] += t;
        __syncthreads();
    }
    if (gid < L) data[gid] = s[threadIdx.x] - v;            // exclusive in block
    if (threadIdx.x == 1023) aux[blockIdx.x] = s[1023];     // block total
}

__global__ void scan2_k(int* aux, int naux) {
    __shared__ int s[1024];
    int v = (threadIdx.x < naux) ? aux[threadIdx.x] : 0;
    s[threadIdx.x] = v;
    __syncthreads();
    for (int off = 1; off < 1024; off <<= 1) {
        int t = (threadIdx.x >= off) ? s[threadIdx.x - off] : 0;
        __syncthreads();
        s[threadIdx.x] += t;
        __syncthreads();
    }
    if (threadIdx.x < naux) aux[threadIdx.x] = s[threadIdx.x] - v;
}

// aux offset is applied at the consumers (scan3 eliminated)

__global__ void part_scatter_k(const int* __restrict__ src, const int* __restrict__ dst,
                               const int* __restrict__ table, const int* __restrict__ aux,
                               unsigned* __restrict__ packed, int e, int nb) {
    __shared__ int loff[1024];
    for (int k = threadIdx.x; k < nb; k += 256) {
        int idx = k * PB + blockIdx.x;
        loff[k] = table[idx] + aux[idx >> 10];
    }
    __syncthreads();
    int eb = (e + PB - 1) / PB;
    int lo = blockIdx.x * eb, hi = min(lo + eb, e);
    for (int i = lo + threadIdx.x; i < hi; i += 256) {
        int d = dst[i];
        int p = atomicAdd(&loff[d >> BSH], 1);
        packed[p] = ((unsigned)(d & (BNODES - 1)) << 25) | (unsigned)src[i];
    }
}

// ---------------- stage 2: per-bucket counting sort -> per-node CSR + dinv ----

__global__ void bucket_sort_k(const unsigned* __restrict__ packed,
                              const int* __restrict__ table, const int* __restrict__ aux,
                              int* __restrict__ col, int* __restrict__ rowptr,
                              float* __restrict__ dinv, int n, int e, int nb) {
    __shared__ int cnt[BNODES];
    __shared__ int s[BNODES];
    __shared__ int cur[BNODES];
    const int k = blockIdx.x;
    const int t = threadIdx.x;
    if (t < BNODES) cnt[t] = 0;
    __syncthreads();
    int i0 = k * PB;
    int i1 = (k + 1) * PB;
    const int bs = table[i0] + aux[i0 >> 10];
    const int be = (k + 1 < nb) ? (table[i1] + aux[i1 >> 10]) : e;
    for (int i = bs + t; i < be; i += 256)
        atomicAdd(&cnt[packed[i] >> 25], 1);
    __syncthreads();
    if (t < BNODES) s[t] = cnt[t];
    __syncthreads();
    for (int off = 1; off < BNODES; off <<= 1) {
        int v = (t < BNODES && t >= off) ? s[t - off] : 0;
        __syncthreads();
        if (t < BNODES) s[t] += v;
        __syncthreads();
    }
    if (t < BNODES) {
        int base = bs + s[t] - cnt[t];
        cur[t] = base;
        int node = (k << BSH) + t;
        if (node < n) {
            rowptr[node] = base;
            dinv[node] = 1.0f / sqrtf(1.0f + (float)cnt[t]);
            if (node == n - 1) rowptr[n] = base + cnt[t];
        }
    }
    __syncthreads();
    for (int i = bs + t; i < be; i += 256) {
        unsigned u = packed[i];
        int p = atomicAdd(&cur[u >> 25], 1);
        col[p] = (int)(u & SRCM);
    }
}

// ---------------- dense transform: out[n,64] = (X[n,K] @ W[K,64]) * dinv[row] ----------------

template<int K>
__global__ __launch_bounds__(256, 2) void gemm_tile_k(const float* __restrict__ X,
                                                      const float* __restrict__ W,
                                                      const float* __restrict__ dinv,
                                                      float* __restrict__ out, int n) {
    __shared__ float sX[64][K + 4];
    __shared__ float sW[K][64];
    const int row0 = blockIdx.x * 64;
    const int t  = threadIdx.x;
    const int tx = t & 15;
    const int ty = t >> 4;
    constexpr int KSH = (K == 128) ? 7 : 6;

    const float* xb = X + (size_t)row0 * K;
#pragma unroll
    for (int it = 0; it < K / 16; ++it) {
        int fl = it * 1024 + t * 4;
        int r  = fl >> KSH;
        int k  = fl & (K - 1);
        float4 v = make_float4(0.f, 0.f, 0.f, 0.f);
        if (row0 + r < n) v = *(const float4*)(xb + fl);
        *(float4*)&sX[r][k] = v;
    }
#pragma unroll
    for (int it = 0; it < K / 16; ++it) {
        int fl = it * 1024 + t * 4;
        *(float4*)&sW[fl >> 6][fl & 63] = *(const float4*)(W + fl);
    }
    __syncthreads();

    float acc[4][4] = {};
#pragma unroll 8
    for (int k = 0; k < K; k += 4) {
        float4 a[4], b[4];
#pragma unroll
        for (int i = 0; i < 4; i++) a[i] = *(float4*)&sX[ty * 4 + i][k];
#pragma unroll
        for (int j = 0; j < 4; j++) b[j] = *(float4*)&sW[k + j][tx * 4];
#pragma unroll
        for (int i = 0; i < 4; i++) {
            acc[i][0] = fmaf(a[i].x, b[0].x, acc[i][0]);
            acc[i][1] = fmaf(a[i].x, b[0].y, acc[i][1]);
            acc[i][2] = fmaf(a[i].x, b[0].z, acc[i][2]);
            acc[i][3] = fmaf(a[i].x, b[0].w, acc[i][3]);
            acc[i][0] = fmaf(a[i].y, b[1].x, acc[i][0]);
            acc[i][1] = fmaf(a[i].y, b[1].y, acc[i][1]);
            acc[i][2] = fmaf(a[i].y, b[1].z, acc[i][2]);
            acc[i][3] = fmaf(a[i].y, b[1].w, acc[i][3]);
            acc[i][0] = fmaf(a[i].z, b[2].x, acc[i][0]);
            acc[i][1] = fmaf(a[i].z, b[2].y, acc[i][1]);
            acc[i][2] = fmaf(a[i].z, b[2].z, acc[i][2]);
            acc[i][3] = fmaf(a[i].z, b[2].w, acc[i][3]);
            acc[i][0] = fmaf(a[i].w, b[3].x, acc[i][0]);
            acc[i][1] = fmaf(a[i].w, b[3].y, acc[i][1]);
            acc[i][2] = fmaf(a[i].w, b[3].z, acc[i][2]);
            acc[i][3] = fmaf(a[i].w, b[3].w, acc[i][3]);
        }
    }

#pragma unroll
    for (int i = 0; i < 4; i++) {
        int gr = row0 + ty * 4 + i;
        if (gr < n) {
            float sc = dinv[gr];
            *(float4*)(out + (size_t)gr * HID + tx * 4) =
                make_float4(acc[i][0] * sc, acc[i][1] * sc, acc[i][2] * sc, acc[i][3] * sc);
        }
    }
}

// ---------------- CSR gather aggregation (fused selfloop + bias + relu [+ logits]) ----

template<bool LOGITS>
__global__ void gather_k(const float* __restrict__ tS, const int* __restrict__ rowptr,
                         const int* __restrict__ col, const float* __restrict__ dinv,
                         const float* __restrict__ b, float* __restrict__ out,
                         const float* __restrict__ Wa, const float* __restrict__ ba,
                         float* __restrict__ logits, int n) {
    int node = (int)((blockIdx.x * (size_t)blockDim.x + threadIdx.x) >> 6);
    int lane = threadIdx.x & 63;
    if (node >= n) return;
    int beg = rowptr[node], end = rowptr[node + 1];
    const float* tl = tS + lane;
    float acc = tl[(size_t)node * HID];   // self-loop term
    int e = beg;
    for (; e + 8 <= end; e += 8) {
        int s0 = col[e],     s1 = col[e + 1], s2 = col[e + 2], s3 = col[e + 3];
        int s4 = col[e + 4], s5 = col[e + 5], s6 = col[e + 6], s7 = col[e + 7];
        float v0 = tl[(size_t)s0 * HID];
        float v1 = tl[(size_t)s1 * HID];
        float v2 = tl[(size_t)s2 * HID];
        float v3 = tl[(size_t)s3 * HID];
        float v4 = tl[(size_t)s4 * HID];
        float v5 = tl[(size_t)s5 * HID];
        float v6 = tl[(size_t)s6 * HID];
        float v7 = tl[(size_t)s7 * HID];
        acc += ((v0 + v1) + (v2 + v3)) + ((v4 + v5) + (v6 + v7));
    }
    for (; e + 4 <= end; e += 4) {
        int s0 = col[e], s1 = col[e + 1], s2 = col[e + 2], s3 = col[e + 3];
        float v0 = tl[(size_t)s0 * HID];
        float v1 = tl[(size_t)s1 * HID];
        float v2 = tl[(size_t)s2 * HID];
        float v3 = tl[(size_t)s3 * HID];
        acc += (v0 + v1) + (v2 + v3);
    }
    for (; e < end; ++e) acc += tl[(size_t)col[e] * HID];
    float h = fmaxf(fmaf(dinv[node], acc, b[lane]), 0.0f);
    out[(size_t)node * HID + lane] = h;
    if (LOGITS) {
        float p = h * Wa[lane];
#pragma unroll
        for (int off = 32; off > 0; off >>= 1) p += __shfl_down(p, off);
        if (lane == 0) logits[node] = p + ba[0];
    }
}

// ---------------- heads ----------------

__global__ void pool_k(const float* __restrict__ h, const int* __restrict__ batch,
                       float* __restrict__ pooled, float* __restrict__ counts, int n) {
    int lane = threadIdx.x & 63;
    int wave = threadIdx.x >> 6;
    int start = blockIdx.x * 64 + wave * 16;
    int end   = min(start + 16, n);
    if (start >= end) return;
    float acc = 0.0f;
    int curg = -1, cnt = 0;
    for (int i = start; i < end; i++) {
        int g = batch[i];
        if (g != curg) {
            if (curg >= 0) {
                atomicAdd(&pooled[curg * HID + lane], acc);
                if (lane == 0) atomicAdd(&counts[curg], (float)cnt);
            }
            curg = g; acc = 0.0f; cnt = 0;
        }
        acc += h[(size_t)i * HID + lane];
        cnt++;
    }
    atomicAdd(&pooled[curg * HID + lane], acc);
    if (lane == 0) atomicAdd(&counts[curg], (float)cnt);
}

__global__ void value_k(const float* __restrict__ pooled, const float* __restrict__ counts,
                        const float* __restrict__ Wc, const float* __restrict__ bc,
                        float* __restrict__ val, int g) {
    int gw   = (int)((blockIdx.x * (size_t)blockDim.x + threadIdx.x) >> 6);
    int lane = threadIdx.x & 63;
    if (gw >= g) return;
    float cnt = fmaxf(counts[gw], 1.0f);
    float p = (pooled[gw * HID + lane] / cnt) * Wc[lane];
#pragma unroll
    for (int off = 32; off > 0; off >>= 1) p += __shfl_down(p, off);
    if (lane == 0) val[gw] = p + bc[0];
}

extern "C" void kernel_launch(void* const* d_in, const int* in_sizes, int n_in,
                              void* d_out, int out_size, void* d_ws, size_t ws_size,
                              hipStream_t stream) {
    const float* x     = (const float*)d_in[0];
    const int*   ei    = (const int*)d_in[1];
    const int*   batch = (const int*)d_in[2];
    const float* W1    = (const float*)d_in[3];
    const float* b1    = (const float*)d_in[4];
    const float* W2    = (const float*)d_in[5];
    const float* b2    = (const float*)d_in[6];
    const float* Wa    = (const float*)d_in[7];
    const float* ba    = (const float*)d_in[8];
    const float* Wc    = (const float*)d_in[9];
    const float* bc    = (const float*)d_in[10];

    const int n = in_sizes[0] / FEAT;   // 100000
    const int e = in_sizes[1] / 2;      // 1600000
    const int g = out_size - n;         // 64
    const int* src = ei;
    const int* dst = ei + e;

    const int nb = (n + BNODES - 1) >> BSH;   // buckets (782)
    const int L  = nb * PB;                    // offset table length

    // workspace layout (packed aliases bufA: dead before first gemm)
    float*    ws     = (float*)d_ws;
    float*    dinv   = ws;                               // n
    float*    bufA   = dinv + n;                         // n*HID  (tS)
    float*    bufB   = bufA + (size_t)n * HID;           // n*HID  (h)
    float*    pooled = bufB + (size_t)n * HID;           // g*HID
    float*    counts = pooled + (size_t)g * HID;         // g
    int*      table  = (int*)(counts + g);               // L
    int*      aux    = table + L;                        // 1024
    int*      rowptr = aux + 1024;                       // n+1
    int*      col    = rowptr + n + 1;                   // e
    unsigned* packed = (unsigned*)bufA;                  // e (aliased, transient)

    const int B = 256;
    const int gridT = (n + 63) / 64;
    const int gridG = (int)(((size_t)n * 64 + B - 1) / B);   // wave per node
    const int nb1   = (L + 1023) / 1024;

    hipMemsetAsync(pooled, 0, (size_t)(g * HID + g) * sizeof(float), stream);

    // two-level CSR build: bucket partition -> in-bucket counting sort
    part_hist_k<<<PB, B, 0, stream>>>(dst, table, e, nb);
    scan1_k<<<nb1, 1024, 0, stream>>>(table, aux, L);
    scan2_k<<<1, 1024, 0, stream>>>(aux, nb1);
    part_scatter_k<<<PB, B, 0, stream>>>(src, dst, table, aux, packed, e, nb);
    bucket_sort_k<<<nb, B, 0, stream>>>(packed, table, aux, col, rowptr, dinv, n, e, nb);

    // layer 1
    gemm_tile_k<FEAT><<<gridT, B, 0, stream>>>(x, W1, dinv, bufA, n);
    gather_k<false><<<gridG, B, 0, stream>>>(bufA, rowptr, col, dinv, b1, bufB,
                                             nullptr, nullptr, nullptr, n);

    // layer 2 (logits fused into gather epilogue)
    gemm_tile_k<HID><<<gridT, B, 0, stream>>>(bufB, W2, dinv, bufA, n);
    gather_k<true><<<gridG, B, 0, stream>>>(bufA, rowptr, col, dinv, b2, bufB,
                                            Wa, ba, (float*)d_out, n);

    // heads
    pool_k<<<(n + 63) / 64, B, 0, stream>>>(bufB, batch, pooled, counts, n);
    value_k<<<(g * 64 + B - 1) / B, B, 0, stream>>>(pooled, counts, Wc, bc, (float*)d_out + n, g);
}

// Round 9
// 361.640 us; speedup vs baseline: 4.4439x; 1.0029x over previous
//
#include <hip/hip_runtime.h>
#include <math.h>

#define FEAT 128
#define HID  64
#define BSH  7                 // 128 dst-nodes per bucket
#define BNODES (1 << BSH)
#define PB   256               // partition blocks
#define SRCM ((1u << 25) - 1)  // src in low 25 bits, dst_local in high 7

// ---------------- stage 1: edge partition by dst-bucket ----------------

__global__ void part_hist_k(const int* __restrict__ dst, int* __restrict__ table,
                            int e, int nb) {
    __shared__ int lcnt[1024];
    for (int i = threadIdx.x; i < nb; i += 256) lcnt[i] = 0;
    __syncthreads();
    int eb = (e + PB - 1) / PB;
    int lo = blockIdx.x * eb, hi = min(lo + eb, e);
    for (int i = lo + threadIdx.x; i < hi; i += 256)
        atomicAdd(&lcnt[dst[i] >> BSH], 1);
    __syncthreads();
    for (int k = threadIdx.x; k < nb; k += 256)
        table[k * PB + blockIdx.x] = lcnt[k];
}

__global__ void scan1_k(int* __restrict__ data, int* __restrict__ aux, int L) {
    __shared__ int s[1024];
    int gid = blockIdx.x * 1024 + threadIdx.x;
    int v = (gid < L) ? data[gid] : 0;
    s[threadIdx.x] = v;
    __syncthreads();
    for (int off = 1; off < 1024; off <<= 1) {
        int t = (threadIdx.x >= off) ? s[threadIdx.x - off] : 0;
        __syncthreads();
        s[threadIdx.x] += t;
        __syncthreads();
    }
    if (gid < L) data[gid] = s[threadIdx.x] - v;            // exclusive in block
    if (threadIdx.x == 1023) aux[blockIdx.x] = s[1023];     // block total
}

__global__ void scan2_k(int* aux, int naux) {
    __shared__ int s[1024];
    int v = (threadIdx.x < naux) ? aux[threadIdx.x] : 0;
    s[threadIdx.x] = v;
    __syncthreads();
    for (int off = 1; off < 1024; off <<= 1) {
        int t = (threadIdx.x >= off) ? s[threadIdx.x - off] : 0;
        __syncthreads();
        s[threadIdx.x] += t;
        __syncthreads();
    }
    if (threadIdx.x < naux) aux[threadIdx.x] = s[threadIdx.x] - v;
}

__global__ void part_scatter_k(const int* __restrict__ src, const int* __restrict__ dst,
                               const int* __restrict__ table, const int* __restrict__ aux,
                               unsigned* __restrict__ packed, int e, int nb) {
    __shared__ int loff[1024];
    for (int k = threadIdx.x; k < nb; k += 256) {
        int idx = k * PB + blockIdx.x;
        loff[k] = table[idx] + aux[idx >> 10];
    }
    __syncthreads();
    int eb = (e + PB - 1) / PB;
    int lo = blockIdx.x * eb, hi = min(lo + eb, e);
    for (int i = lo + threadIdx.x; i < hi; i += 256) {
        int d = dst[i];
        int p = atomicAdd(&loff[d >> BSH], 1);
        packed[p] = ((unsigned)(d & (BNODES - 1)) << 25) | (unsigned)src[i];
    }
}

// ---------------- stage 2: per-bucket counting sort -> per-node CSR + dinv ----

__global__ void bucket_sort_k(const unsigned* __restrict__ packed,
                              const int* __restrict__ table, const int* __restrict__ aux,
                              int* __restrict__ col, int* __restrict__ rowptr,
                              float* __restrict__ dinv, int n, int e, int nb) {
    __shared__ int cnt[BNODES];
    __shared__ int s[BNODES];
    __shared__ int cur[BNODES];
    const int k = blockIdx.x;
    const int t = threadIdx.x;
    if (t < BNODES) cnt[t] = 0;
    __syncthreads();
    int i0 = k * PB;
    int i1 = (k + 1) * PB;
    const int bs = table[i0] + aux[i0 >> 10];
    const int be = (k + 1 < nb) ? (table[i1] + aux[i1 >> 10]) : e;
    for (int i = bs + t; i < be; i += 256)
        atomicAdd(&cnt[packed[i] >> 25], 1);
    __syncthreads();
    if (t < BNODES) s[t] = cnt[t];
    __syncthreads();
    for (int off = 1; off < BNODES; off <<= 1) {
        int v = (t < BNODES && t >= off) ? s[t - off] : 0;
        __syncthreads();
        if (t < BNODES) s[t] += v;
        __syncthreads();
    }
    if (t < BNODES) {
        int base = bs + s[t] - cnt[t];
        cur[t] = base;
        int node = (k << BSH) + t;
        if (node < n) {
            rowptr[node] = base;
            dinv[node] = 1.0f / sqrtf(1.0f + (float)cnt[t]);
            if (node == n - 1) rowptr[n] = base + cnt[t];
        }
    }
    __syncthreads();
    for (int i = bs + t; i < be; i += 256) {
        unsigned u = packed[i];
        int p = atomicAdd(&cur[u >> 25], 1);
        col[p] = (int)(u & SRCM);
    }
}

// ---------------- dense transform: out[n,64] = (X[n,K] @ W[K,64]) * dinv[row] ----------------
// X staged whole (contiguous 64*K floats). W staged in 64-row slabs so
// LDS = 50.2 KB (K=128) -> 3 blocks/CU, 33.8 KB (K=64) -> 4 blocks/CU.
// Summation order identical to the single-slab version (k ascending).

template<int K>
__global__ __launch_bounds__(256, (K == 128) ? 3 : 4)
void gemm_tile_k(const float* __restrict__ X, const float* __restrict__ W,
                 const float* __restrict__ dinv, float* __restrict__ out, int n) {
    __shared__ float sX[64][K + 4];
    __shared__ float sW[64][64];       // one 64-row slab of W
    const int row0 = blockIdx.x * 64;
    const int t  = threadIdx.x;
    const int tx = t & 15;
    const int ty = t >> 4;
    constexpr int KSH = (K == 128) ? 7 : 6;

    const float* xb = X + (size_t)row0 * K;
#pragma unroll
    for (int it = 0; it < K / 16; ++it) {
        int fl = it * 1024 + t * 4;
        int r  = fl >> KSH;
        int k  = fl & (K - 1);
        float4 v = make_float4(0.f, 0.f, 0.f, 0.f);
        if (row0 + r < n) v = *(const float4*)(xb + fl);
        *(float4*)&sX[r][k] = v;
    }

    float acc[4][4] = {};
#pragma unroll
    for (int ph = 0; ph < K / 64; ++ph) {
        __syncthreads();   // X-stage done (ph=0) / previous slab consumed (ph>0)
#pragma unroll
        for (int it = 0; it < 4; ++it) {
            int fl = it * 1024 + t * 4;
            *(float4*)&sW[fl >> 6][fl & 63] = *(const float4*)(W + ph * 64 * HID + fl);
        }
        __syncthreads();

#pragma unroll 8
        for (int k = 0; k < 64; k += 4) {
            float4 a[4], b[4];
#pragma unroll
            for (int i = 0; i < 4; i++) a[i] = *(float4*)&sX[ty * 4 + i][ph * 64 + k];
#pragma unroll
            for (int j = 0; j < 4; j++) b[j] = *(float4*)&sW[k + j][tx * 4];
#pragma unroll
            for (int i = 0; i < 4; i++) {
                acc[i][0] = fmaf(a[i].x, b[0].x, acc[i][0]);
                acc[i][1] = fmaf(a[i].x, b[0].y, acc[i][1]);
                acc[i][2] = fmaf(a[i].x, b[0].z, acc[i][2]);
                acc[i][3] = fmaf(a[i].x, b[0].w, acc[i][3]);
                acc[i][0] = fmaf(a[i].y, b[1].x, acc[i][0]);
                acc[i][1] = fmaf(a[i].y, b[1].y, acc[i][1]);
                acc[i][2] = fmaf(a[i].y, b[1].z, acc[i][2]);
                acc[i][3] = fmaf(a[i].y, b[1].w, acc[i][3]);
                acc[i][0] = fmaf(a[i].z, b[2].x, acc[i][0]);
                acc[i][1] = fmaf(a[i].z, b[2].y, acc[i][1]);
                acc[i][2] = fmaf(a[i].z, b[2].z, acc[i][2]);
                acc[i][3] = fmaf(a[i].z, b[2].w, acc[i][3]);
                acc[i][0] = fmaf(a[i].w, b[3].x, acc[i][0]);
                acc[i][1] = fmaf(a[i].w, b[3].y, acc[i][1]);
                acc[i][2] = fmaf(a[i].w, b[3].z, acc[i][2]);
                acc[i][3] = fmaf(a[i].w, b[3].w, acc[i][3]);
            }
        }
    }

#pragma unroll
    for (int i = 0; i < 4; i++) {
        int gr = row0 + ty * 4 + i;
        if (gr < n) {
            float sc = dinv[gr];
            *(float4*)(out + (size_t)gr * HID + tx * 4) =
                make_float4(acc[i][0] * sc, acc[i][1] * sc, acc[i][2] * sc, acc[i][3] * sc);
        }
    }
}

// ---------------- CSR gather aggregation (fused selfloop + bias + relu [+ logits]) ----

template<bool LOGITS>
__global__ void gather_k(const float* __restrict__ tS, const int* __restrict__ rowptr,
                         const int* __restrict__ col, const float* __restrict__ dinv,
                         const float* __restrict__ b, float* __restrict__ out,
                         const float* __restrict__ Wa, const float* __restrict__ ba,
                         float* __restrict__ logits, int n) {
    int node = (int)((blockIdx.x * (size_t)blockDim.x + threadIdx.x) >> 6);
    int lane = threadIdx.x & 63;
    if (node >= n) return;
    int beg = rowptr[node], end = rowptr[node + 1];
    const float* tl = tS + lane;
    float acc = tl[(size_t)node * HID];   // self-loop term
    int e = beg;
    for (; e + 8 <= end; e += 8) {
        int s0 = col[e],     s1 = col[e + 1], s2 = col[e + 2], s3 = col[e + 3];
        int s4 = col[e + 4], s5 = col[e + 5], s6 = col[e + 6], s7 = col[e + 7];
        float v0 = tl[(size_t)s0 * HID];
        float v1 = tl[(size_t)s1 * HID];
        float v2 = tl[(size_t)s2 * HID];
        float v3 = tl[(size_t)s3 * HID];
        float v4 = tl[(size_t)s4 * HID];
        float v5 = tl[(size_t)s5 * HID];
        float v6 = tl[(size_t)s6 * HID];
        float v7 = tl[(size_t)s7 * HID];
        acc += ((v0 + v1) + (v2 + v3)) + ((v4 + v5) + (v6 + v7));
    }
    for (; e + 4 <= end; e += 4) {
        int s0 = col[e], s1 = col[e + 1], s2 = col[e + 2], s3 = col[e + 3];
        float v0 = tl[(size_t)s0 * HID];
        float v1 = tl[(size_t)s1 * HID];
        float v2 = tl[(size_t)s2 * HID];
        float v3 = tl[(size_t)s3 * HID];
        acc += (v0 + v1) + (v2 + v3);
    }
    for (; e < end; ++e) acc += tl[(size_t)col[e] * HID];
    float h = fmaxf(fmaf(dinv[node], acc, b[lane]), 0.0f);
    out[(size_t)node * HID + lane] = h;
    if (LOGITS) {
        float p = h * Wa[lane];
#pragma unroll
        for (int off = 32; off > 0; off >>= 1) p += __shfl_down(p, off);
        if (lane == 0) logits[node] = p + ba[0];
    }
}

// ---------------- heads ----------------
// pool: 64 nodes per wave -> ~1.6k pooled flushes total (vs 7k at 16/wave).

__global__ void pool_k(const float* __restrict__ h, const int* __restrict__ batch,
                       float* __restrict__ pooled, float* __restrict__ counts, int n) {
    int lane = threadIdx.x & 63;
    int wave = threadIdx.x >> 6;
    int start = blockIdx.x * 256 + wave * 64;
    int end   = min(start + 64, n);
    if (start >= end) return;
    float acc = 0.0f;
    int curg = -1, cnt = 0;
    for (int i = start; i < end; i++) {
        int g = batch[i];
        if (g != curg) {
            if (curg >= 0) {
                atomicAdd(&pooled[curg * HID + lane], acc);
                if (lane == 0) atomicAdd(&counts[curg], (float)cnt);
            }
            curg = g; acc = 0.0f; cnt = 0;
        }
        acc += h[(size_t)i * HID + lane];
        cnt++;
    }
    atomicAdd(&pooled[curg * HID + lane], acc);
    if (lane == 0) atomicAdd(&counts[curg], (float)cnt);
}

__global__ void value_k(const float* __restrict__ pooled, const float* __restrict__ counts,
                        const float* __restrict__ Wc, const float* __restrict__ bc,
                        float* __restrict__ val, int g) {
    int gw   = (int)((blockIdx.x * (size_t)blockDim.x + threadIdx.x) >> 6);
    int lane = threadIdx.x & 63;
    if (gw >= g) return;
    float cnt = fmaxf(counts[gw], 1.0f);
    float p = (pooled[gw * HID + lane] / cnt) * Wc[lane];
#pragma unroll
    for (int off = 32; off > 0; off >>= 1) p += __shfl_down(p, off);
    if (lane == 0) val[gw] = p + bc[0];
}

extern "C" void kernel_launch(void* const* d_in, const int* in_sizes, int n_in,
                              void* d_out, int out_size, void* d_ws, size_t ws_size,
                              hipStream_t stream) {
    const float* x     = (const float*)d_in[0];
    const int*   ei    = (const int*)d_in[1];
    const int*   batch = (const int*)d_in[2];
    const float* W1    = (const float*)d_in[3];
    const float* b1    = (const float*)d_in[4];
    const float* W2    = (const float*)d_in[5];
    const float* b2    = (const float*)d_in[6];
    const float* Wa    = (const float*)d_in[7];
    const float* ba    = (const float*)d_in[8];
    const float* Wc    = (const float*)d_in[9];
    const float* bc    = (const float*)d_in[10];

    const int n = in_sizes[0] / FEAT;   // 100000
    const int e = in_sizes[1] / 2;      // 1600000
    const int g = out_size - n;         // 64
    const int* src = ei;
    const int* dst = ei + e;

    const int nb = (n + BNODES - 1) >> BSH;   // buckets (782)
    const int L  = nb * PB;                    // offset table length

    // workspace layout (packed aliases bufA: dead before first gemm)
    float*    ws     = (float*)d_ws;
    float*    dinv   = ws;                               // n
    float*    bufA   = dinv + n;                         // n*HID  (tS)
    float*    bufB   = bufA + (size_t)n * HID;           // n*HID  (h)
    float*    pooled = bufB + (size_t)n * HID;           // g*HID
    float*    counts = pooled + (size_t)g * HID;         // g
    int*      table  = (int*)(counts + g);               // L
    int*      aux    = table + L;                        // 1024
    int*      rowptr = aux + 1024;                       // n+1
    int*      col    = rowptr + n + 1;                   // e
    unsigned* packed = (unsigned*)bufA;                  // e (aliased, transient)

    const int B = 256;
    const int gridT = (n + 63) / 64;
    const int gridG = (int)(((size_t)n * 64 + B - 1) / B);   // wave per node
    const int nb1   = (L + 1023) / 1024;

    hipMemsetAsync(pooled, 0, (size_t)(g * HID + g) * sizeof(float), stream);

    // two-level CSR build: bucket partition -> in-bucket counting sort
    part_hist_k<<<PB, B, 0, stream>>>(dst, table, e, nb);
    scan1_k<<<nb1, 1024, 0, stream>>>(table, aux, L);
    scan2_k<<<1, 1024, 0, stream>>>(aux, nb1);
    part_scatter_k<<<PB, B, 0, stream>>>(src, dst, table, aux, packed, e, nb);
    bucket_sort_k<<<nb, B, 0, stream>>>(packed, table, aux, col, rowptr, dinv, n, e, nb);

    // layer 1
    gemm_tile_k<FEAT><<<gridT, B, 0, stream>>>(x, W1, dinv, bufA, n);
    gather_k<false><<<gridG, B, 0, stream>>>(bufA, rowptr, col, dinv, b1, bufB,
                                             nullptr, nullptr, nullptr, n);

    // layer 2 (logits fused into gather epilogue)
    gemm_tile_k<HID><<<gridT, B, 0, stream>>>(bufB, W2, dinv, bufA, n);
    gather_k<true><<<gridG, B, 0, stream>>>(bufA, rowptr, col, dinv, b2, bufB,
                                            Wa, ba, (float*)d_out, n);

    // heads
    pool_k<<<(n + 255) / 256, B, 0, stream>>>(bufB, batch, pooled, counts, n);
    value_k<<<(g * 64 + B - 1) / B, B, 0, stream>>>(pooled, counts, Wc, bc, (float*)d_out + n, g);
}